// Round 12
// baseline (308.542 us; speedup 1.0000x reference)
//
#include <hip/hip_runtime.h>
#include <hip/hip_bf16.h>

typedef unsigned int   uint;
typedef unsigned short ushort;
typedef short bf16x8 __attribute__((ext_vector_type(8)));
typedef float f32x4  __attribute__((ext_vector_type(4)));

// Problem constants
constexpr int Bm   = 512;   // molecules
constexpr int Aa   = 128;   // atoms / molecule
constexpr int Ee   = 256;   // directed bonds / molecule
constexpr int Kk   = 6;     // incoming gathered
constexpr int AFD  = 133;
constexpr int FD   = 147;   // 133+14
constexpr int Hh   = 128;
constexpr int CATD = 261;   // 133+128
constexpr int KWI  = 192;   // Wi_b row stride (147 real + 45 zero)
constexpr int KWO  = 320;   // Wo_b row stride: [0,133) atomf, [133,192) zero, [192,320) m2a
constexpr int MST  = 136;   // msg LDS row stride (bf16)
constexpr int FST  = 152;   // fini stage row stride (bf16), 16B-aligned rows

// ---- bf16 helpers ----------------------------------------------------------
__device__ __forceinline__ ushort f2b(float f) {
    uint u = __float_as_uint(f);
    u += 0x7FFFu + ((u >> 16) & 1u);
    return (ushort)(u >> 16);
}
__device__ __forceinline__ uint cvt2(float x, float y) {   // v_cvt_pk_bf16_f32
    float2 t2; t2.x = x; t2.y = y;
    __hip_bfloat162 t = __float22bfloat162_rn(t2);
    uint r; __builtin_memcpy(&r, &t, 4); return r;
}
__device__ __forceinline__ float2 b2f2(uint p) {
    float2 r;
    r.x = __uint_as_float(p << 16);
    r.y = __uint_as_float(p & 0xFFFF0000u);
    return r;
}

// sum 6 bf16 rows (16B slices) from LDS msg, repack to an MFMA A-frag
__device__ __forceinline__ bf16x8 gsum6(const ushort* src, const int* mr, int ko) {
    float2 s0 = {0.f, 0.f}, s1 = {0.f, 0.f}, s2 = {0.f, 0.f}, s3 = {0.f, 0.f};
#pragma unroll
    for (int k = 0; k < Kk; ++k) {
        uint4 m = *(const uint4*)&src[mr[k] + ko];
        float2 a = b2f2(m.x); s0.x += a.x; s0.y += a.y;
        float2 b = b2f2(m.y); s1.x += b.x; s1.y += b.y;
        float2 d = b2f2(m.z); s2.x += d.x; s2.y += d.y;
        float2 e = b2f2(m.w); s3.x += e.x; s3.y += e.y;
    }
    uint4 o;
    o.x = cvt2(s0.x, s0.y); o.y = cvt2(s1.x, s1.y);
    o.z = cvt2(s2.x, s2.y); o.w = cvt2(s3.x, s3.y);
    bf16x8 r;
    __builtin_memcpy(&r, &o, 16);
    return r;
}

// build A-frag straight from global fp32 (8 predicated dword loads + 4 cvt_pk)
__device__ __forceinline__ bf16x8 ld_frag_f32(const float* sp, int c0, int lim) {
    float v[8];
#pragma unroll
    for (int d = 0; d < 8; ++d) v[d] = (c0 + d < lim) ? sp[d] : 0.f;
    uint4 o;
    o.x = cvt2(v[0], v[1]); o.y = cvt2(v[2], v[3]);
    o.z = cvt2(v[4], v[5]); o.w = cvt2(v[6], v[7]);
    bf16x8 r;
    __builtin_memcpy(&r, &o, 16);
    return r;
}

// ---------------------------------------------------------------------------
// Weight prep: fp32 -> padded bf16 (tiny; runs once)
// ---------------------------------------------------------------------------
__global__ __launch_bounds__(256) void k_prep_w(const float* __restrict__ Wi,
                                                const float* __restrict__ Wh,
                                                const float* __restrict__ Wo,
                                                ushort* __restrict__ Wi_b,
                                                ushort* __restrict__ Wh_b,
                                                ushort* __restrict__ Wo_b) {
    const int h = blockIdx.x, t = threadIdx.x;
    for (int c = t; c < KWI; c += 256)
        Wi_b[h * KWI + c] = f2b(c < FD ? Wi[h * FD + c] : 0.f);
    for (int c = t; c < Hh; c += 256)
        Wh_b[h * Hh + c] = f2b(Wh[h * Hh + c]);
    for (int c = t; c < KWO; c += 256) {
        float v = 0.f;
        if (c < AFD)       v = Wo[h * CATD + c];
        else if (c >= 192) v = Wo[h * CATD + AFD + (c - 192)];
        Wo_b[h * KWO + c] = f2b(v);
    }
}

__global__ __launch_bounds__(512) void k_scan(const int* __restrict__ ml,
                                              int* __restrict__ pfx) {
    __shared__ int s[512];
    int t = threadIdx.x;
    s[t] = ml[t];
    __syncthreads();
    for (int off = 1; off < 512; off <<= 1) {
        int v = (t >= off) ? s[t - off] : 0;
        __syncthreads();
        s[t] += v;
        __syncthreads();
    }
    pfx[t + 1] = s[t];
    if (t == 0) pfx[0] = 0;
}

// ---------------------------------------------------------------------------
// Fused DMPNN, LOW-AGPR restructure. One block = one molecule, 512 threads.
// Occupancy model (11 rounds): waves/SIMD = floor(512 / (VGPR_Count + AGPR));
// round-3's acc[2][8] = 64 AGPR -> 176/wave -> 2 waves/SIMD (22%). This
// version keeps only acc[8] = 32 AGPR live:
//  - Phase 1 in TWO ROW-HALVES: stage half (bf16, stride 152) into msg1,
//    barrier, compute inp for the half with acc[8], write msg0, barrier.
//  - Hops PING-PONG msg0<->msg1: reads/writes in different buffers, so the
//    wave's two 16-row tiles run sequentially with one reused acc[8], and
//    each hop needs ONE barrier (publish) instead of two.
//  - Phase 3: ro[8] reuses acc; m2a gather from msg0 + atomf direct global.
// => ~112 arch + 32 acc = ~144/wave -> 3 waves/SIMD (12 waves/CU, +50% TLP).
// LDS: msg0 69,632 + msg1 69,632 + maps 9,216 = 148,480 B.
// Stage-tail guard: msg1 ushorts [19456,19464) zeroed once (row-127 ks=4
// frag over-read); all other over-reads hit zeroed pad cols or finite data
// that multiplies zero-padded weight columns (no Inf/NaN path).
// ---------------------------------------------------------------------------
__global__ __launch_bounds__(512, 2) void k_fused(
        const float* __restrict__ atomf,
        const float* __restrict__ fini,
        const int*   __restrict__ a2ib,
        const int*   __restrict__ mapping,
        const ushort* __restrict__ Wi_b,
        const ushort* __restrict__ Wh_b,
        const ushort* __restrict__ Wo_b,
        const float* __restrict__ bo,
        const int*   __restrict__ mol_lens,
        const int*   __restrict__ pfx,
        float* __restrict__ out,
        float* __restrict__ cmask) {
    __shared__ ushort msg0[Ee * MST];      // 69,632 B
    __shared__ ushort msg1[Ee * MST];      // 69,632 B (fini half stage + hop buffer)
    __shared__ int    map_s[Ee * Kk];      //  6,144 B
    __shared__ int    a2_s[Aa * Kk];       //  3,072 B  -> 148,480 B total

    const int b    = blockIdx.x;
    const int tid  = threadIdx.x;
    const int wave = tid >> 6;             // 0..7
    const int lane = tid & 63;
    const int l15  = lane & 15, quad = lane >> 4;

    for (int i = tid; i < Ee * Kk; i += 512) map_s[i] = mapping[b * Ee * Kk + i];
    for (int i = tid; i < Aa * Kk; i += 512) a2_s[i]  = a2ib[b * Aa * Kk + i];
    if (tid < 8) msg1[128 * FST + tid] = 0;   // stage tail guard
    const int len = mol_lens[b];
    if (tid < Aa) cmask[b * Aa + tid] = (tid < len) ? 1.0f : 0.0f;

    uint2 inp_pk[2][8];                    // 16 VGPR standing

    // ==== Phase 1: inp = fini @ Wi^T, two row-halves through msg1 ========
#pragma unroll
    for (int half = 0; half < 2; ++half) {
        // stage 128 rows fp32 -> bf16 (aligned uint4 stream, 4704 vecs)
        const uint4* fsrc4 = (const uint4*)(fini + (size_t)b * Ee * FD) + half * 4704;
        for (int k = tid; k < 4704; k += 512) {
            uint4 q = fsrc4[k];
            const int d0 = half * 18816 + k * 4;    // absolute dword in molecule
#pragma unroll
            for (int i = 0; i < 4; ++i) {
                const int d = d0 + i;
                const int r = d / FD;               // magic-mul
                uint w = (i == 0) ? q.x : (i == 1) ? q.y : (i == 2) ? q.z : q.w;
                // ushort idx in half-stage: (r-half*128)*FST + (d - r*FD)
                msg1[d + 5 * r - half * 19456] = f2b(__uint_as_float(w));
            }
        }
        for (int i = tid; i < 128 * 5; i += 512) {  // zero pad cols [147,152)
            const int r = i / 5, c = FD + (i - r * 5);
            msg1[r * FST + c] = 0;
        }
        __syncthreads();   // stage ready (and prev-half stage reads done)

        f32x4 acc[8];
#pragma unroll
        for (int j = 0; j < 8; ++j) acc[j] = (f32x4){0.f, 0.f, 0.f, 0.f};
#pragma unroll
        for (int ks = 0; ks < 5; ++ks) {            // K [0,160) covers FD=147
            const int c0 = ks * 32 + quad * 8;
            bf16x8 af = *(const bf16x8*)&msg1[(wave * 16 + l15) * FST + c0];
#pragma unroll
            for (int jh = 0; jh < 2; ++jh) {
                bf16x8 bf[4];
#pragma unroll
                for (int j = 0; j < 4; ++j)
                    bf[j] = *(const bf16x8*)&Wi_b[((jh * 4 + j) * 16 + l15) * KWI + c0];
#pragma unroll
                for (int j = 0; j < 4; ++j)
                    acc[jh * 4 + j] = __builtin_amdgcn_mfma_f32_16x16x32_bf16(
                        af, bf[j], acc[jh * 4 + j], 0, 0, 0);
            }
        }
        // pack inp, write msg0 = relu(inp) for this half's rows
#pragma unroll
        for (int j = 0; j < 8; ++j) {
            f32x4 a4 = acc[j];
            uint2 p;
            p.x = cvt2(a4[0], a4[1]);
            p.y = cvt2(a4[2], a4[3]);
            inp_pk[half][j] = p;
            const int col = j * 16 + l15;
#pragma unroll
            for (int reg = 0; reg < 4; ++reg) {
                const int row = half * 128 + wave * 16 + quad * 4 + reg;
                float v = a4[reg] > 0.f ? a4[reg] : 0.f;
                msg0[row * MST + col] = f2b(v);
            }
        }
        __syncthreads();   // half's stage reads done; msg0 half published
    }
    // msg0 complete; msg1 free

    // ==== Phase 2: two ping-pong hops (1 barrier each) ===================
#pragma unroll
    for (int h = 0; h < 2; ++h) {
        const ushort* src = h ? msg1 : msg0;
        ushort*       dst = h ? msg0 : msg1;
#pragma unroll
        for (int i = 0; i < 2; ++i) {              // two 16-row tiles, seq.
            const int rowA = i * 128 + wave * 16 + l15;
            int mr[Kk];
#pragma unroll
            for (int k = 0; k < Kk; ++k) mr[k] = map_s[rowA * Kk + k] * MST;
            f32x4 acc[8];
#pragma unroll
            for (int j = 0; j < 8; ++j) {
                float2 lo = b2f2(inp_pk[i][j].x);
                float2 hi = b2f2(inp_pk[i][j].y);
                acc[j] = (f32x4){lo.x, lo.y, hi.x, hi.y};
            }
#pragma unroll
            for (int ks = 0; ks < 4; ++ks) {
                const int ko = ks * 32 + quad * 8;
                bf16x8 af = gsum6(src, mr, ko);
#pragma unroll
                for (int jh = 0; jh < 2; ++jh) {
                    bf16x8 bf[4];
#pragma unroll
                    for (int j = 0; j < 4; ++j)
                        bf[j] = *(const bf16x8*)&Wh_b[((jh * 4 + j) * 16 + l15) * Hh + ko];
#pragma unroll
                    for (int j = 0; j < 4; ++j)
                        acc[jh * 4 + j] = __builtin_amdgcn_mfma_f32_16x16x32_bf16(
                            af, bf[j], acc[jh * 4 + j], 0, 0, 0);
                }
            }
#pragma unroll
            for (int j = 0; j < 8; ++j) {
                const int col = j * 16 + l15;
#pragma unroll
                for (int reg = 0; reg < 4; ++reg) {
                    const int row = i * 128 + wave * 16 + quad * 4 + reg;
                    float v = acc[j][reg];
                    dst[row * MST + col] = f2b(v > 0.f ? v : 0.f);
                }
            }
        }
        __syncthreads();   // publish dst for next hop / phase 3
    }
    // final msg (post-relu) in msg0

    // ==== Phase 3: readout (barrier-free) ================================
    f32x4 ro[8];
#pragma unroll
    for (int j = 0; j < 8; ++j) ro[j] = (f32x4){0.f, 0.f, 0.f, 0.f};

    const int arow = wave * 16 + l15;      // atom row for A-frags

    {   // m2a gather region, K cols [192,320) of Wo
        int ar[Kk];
#pragma unroll
        for (int k = 0; k < Kk; ++k) ar[k] = a2_s[arow * Kk + k] * MST;
#pragma unroll
        for (int ks = 0; ks < 4; ++ks) {
            const int ko = ks * 32 + quad * 8;
            bf16x8 a0 = gsum6(msg0, ar, ko);
#pragma unroll
            for (int jh = 0; jh < 2; ++jh) {
                bf16x8 bf[4];
#pragma unroll
                for (int j = 0; j < 4; ++j)
                    bf[j] = *(const bf16x8*)&Wo_b[((jh * 4 + j) * 16 + l15) * KWO + 192 + ko];
#pragma unroll
                for (int j = 0; j < 4; ++j)
                    ro[jh * 4 + j] = __builtin_amdgcn_mfma_f32_16x16x32_bf16(
                        a0, bf[j], ro[jh * 4 + j], 0, 0, 0);
            }
        }
    }

    const float* asrc = atomf + (size_t)b * Aa * AFD;
#pragma unroll
    for (int ksi = 0; ksi < 5; ++ksi) {    // atomf region, K cols [0,160)
        const int c0 = ksi * 32 + quad * 8;
        bf16x8 a0 = ld_frag_f32(asrc + (size_t)arow * AFD + c0, c0, AFD);
#pragma unroll
        for (int jh = 0; jh < 2; ++jh) {
            bf16x8 bf[4];
#pragma unroll
            for (int j = 0; j < 4; ++j)
                bf[j] = *(const bf16x8*)&Wo_b[((jh * 4 + j) * 16 + l15) * KWO + c0];
#pragma unroll
            for (int j = 0; j < 4; ++j)
                ro[jh * 4 + j] = __builtin_amdgcn_mfma_f32_16x16x32_bf16(
                    a0, bf[j], ro[jh * 4 + j], 0, 0, 0);
        }
    }

    const int base = pfx[b];
#pragma unroll
    for (int j = 0; j < 8; ++j) {
        const int col = j * 16 + l15;
        const float bv = bo[col];
#pragma unroll
        for (int reg = 0; reg < 4; ++reg) {
            const int a = wave * 16 + quad * 4 + reg;
            if (a < len) {
                float v = ro[j][reg] + bv;
                out[(size_t)(base + a) * Hh + col] = v > 0.f ? v : 0.f;
            }
        }
    }
}

// ---------------------------------------------------------------------------
extern "C" void kernel_launch(void* const* d_in, const int* in_sizes, int n_in,
                              void* d_out, int out_size, void* d_ws, size_t ws_size,
                              hipStream_t stream) {
    const float* atom_feature = (const float*)d_in[0];
    const float* f_ini        = (const float*)d_in[1];
    const int*   a2ib         = (const int*)d_in[2];
    const int*   mapping      = (const int*)d_in[3];
    const int*   mol_lens     = (const int*)d_in[5];
    const float* Wi           = (const float*)d_in[6];
    const float* Wh           = (const float*)d_in[7];
    const float* Wo           = (const float*)d_in[8];
    const float* bo           = (const float*)d_in[9];
    float* out = (float*)d_out;

    ushort* Wi_b = (ushort*)d_ws;
    ushort* Wh_b = Wi_b + 128 * KWI;
    ushort* Wo_b = Wh_b + 128 * Hh;
    int*    pfx  = (int*)(Wo_b + 128 * KWO);

    float* cmask = out + ((size_t)out_size - (size_t)Bm * Aa);

    k_prep_w<<<128, 256, 0, stream>>>(Wi, Wh, Wo, Wi_b, Wh_b, Wo_b);
    k_scan  <<<1, 512, 0, stream>>>(mol_lens, pfx);
    k_fused <<<Bm, 512, 0, stream>>>(atom_feature, f_ini, a2ib, mapping,
                                     Wi_b, Wh_b, Wo_b, bo, mol_lens, pfx,
                                     out, cmask);
}